// Round 9
// baseline (3273.652 us; speedup 1.0000x reference)
//
#include <hip/hip_runtime.h>

#define Bn 8
#define Nn 8192
#define Cn 64
#define Mn 2048
#define Kn 16
#define FPS_T 512
#define CPT 16                   // points per chunk; chunk t = sorted [16t,16t+16)
#define NWAVE (FPS_T / 64)       // 8
#define NCELL 4096               // 16x16x16 Morton grid
#define CELLS_PT (NCELL / FPS_T) // 8

typedef unsigned long long u64;
typedef unsigned u32;
typedef unsigned short u16;

__device__ __forceinline__ u64 u64max(u64 a, u64 b) { return a > b ? a : b; }

// ---- fused u64 (value,lo) DPP max step; bound_ctrl=false -> identity on edge.
template <int CTRL, int RMASK>
__device__ __forceinline__ void dpp_kmax_step(u32& hi, u32& lo) {
    const u32 h2 = (u32)__builtin_amdgcn_update_dpp((int)hi, (int)hi, CTRL, RMASK, 0xF, false);
    const u32 l2 = (u32)__builtin_amdgcn_update_dpp((int)lo, (int)lo, CTRL, RMASK, 0xF, false);
    const u64 a = ((u64)hi << 32) | lo;
    const u64 b2 = ((u64)h2 << 32) | l2;
    if (b2 > a) { hi = h2; lo = l2; }
}
// 16-lane row kmax: result in lane 15 of each row.
__device__ __forceinline__ void row_kmax(u32& hi, u32& lo) {
    dpp_kmax_step<0x111, 0xF>(hi, lo);   // row_shr:1
    dpp_kmax_step<0x112, 0xF>(hi, lo);   // row_shr:2
    dpp_kmax_step<0x114, 0xF>(hi, lo);   // row_shr:4
    dpp_kmax_step<0x118, 0xF>(hi, lo);   // row_shr:8
}
// wave-64 kmax: result in lane 63 (validated pattern, rounds 4-7).
__device__ __forceinline__ void wave_kmax(u32& hi, u32& lo) {
    row_kmax(hi, lo);
    dpp_kmax_step<0x142, 0xA>(hi, lo);   // row_bcast:15
    dpp_kmax_step<0x143, 0xC>(hi, lo);   // row_bcast:31
}

__device__ __forceinline__ u32 spread4(u32 x) {
    return (x & 1u) | ((x & 2u) << 2) | ((x & 4u) << 4) | ((x & 8u) << 6);
}
__device__ __forceinline__ u32 quant16(float v) {
    int c = (int)((v + 4.0f) * 2.0f);
    c = c < 0 ? 0 : (c > 15 ? 15 : c);
    return (u32)c;
}

// ---------------------------------------------------------------------------
// FPS, wave-local compacted updates. One block/batch, 512 threads (8 waves).
// Points Morton-sorted in LDS; chunk t (16 pts) owned by thread t for the
// skip test; active chunks processed 4-per-pass x 16 lanes by the OWNING
// wave (d2 in LDS); chunk key rebuilt exactly via DPP row reduce. Wave key
// re-reduced only when ballot!=0, else cached. Single barrier per iteration;
// s_wkey double-buffered. Arithmetic + key semantics identical to round 7
// (validated): XLA-exact rn ops, key = (d2bits<<32 | ~g<<19 | pos<<6).
// ---------------------------------------------------------------------------
__global__ __launch_bounds__(FPS_T) void fps_kernel(
    const float* __restrict__ p1,
    float* __restrict__ out_p2,
    float* __restrict__ out_idxf)
{
    __shared__ float s_Px[Nn], s_Py[Nn], s_Pz[Nn];   // 96 KB (sorted order)
    __shared__ float s_blobA[Nn];                     // 32 KB: hist -> d2
    __shared__ u32   s_blobB[Mn];                     // 8 KB: scan -> osel
    __shared__ u16   s_G[Nn];                         // 16 KB sorted->orig idx
    __shared__ u64   s_ub[FPS_T];                     // 4 KB chunk keys
    __shared__ u64   s_wkey[2][NWAVE];

    int*   s_hist = (int*)s_blobA;     // NCELL ints (16 KB) during sort
    float* s_d2   = s_blobA;           // Nn floats after sort
    int*   s_scan = (int*)s_blobB;     // FPS_T ints during sort
    u32*   s_osel = s_blobB;           // Mn entries (g<<13)|pos

    const int b = blockIdx.x;
    const int t = threadIdx.x;
    const int w = t >> 6;
    const int lane = t & 63;
    const float* __restrict__ P = p1 + (size_t)b * (Nn * 3);

    float qx = P[0], qy = P[1], qz = P[2];   // original first point

    // ---- load + quantize ----
    float rx[CPT], ry[CPT], rz[CPT];
    u32 cc[CPT];
#pragma unroll
    for (int j = 0; j < CPT; ++j) {
        const int g = t + j * FPS_T;
        rx[j] = P[g * 3 + 0];
        ry[j] = P[g * 3 + 1];
        rz[j] = P[g * 3 + 2];
        cc[j] = spread4(quant16(rx[j])) | (spread4(quant16(ry[j])) << 1) |
                (spread4(quant16(rz[j])) << 2);
    }
#pragma unroll
    for (int i = 0; i < CELLS_PT; ++i) s_hist[t * CELLS_PT + i] = 0;
    __syncthreads();
#pragma unroll
    for (int j = 0; j < CPT; ++j) atomicAdd(&s_hist[cc[j]], 1);
    __syncthreads();

    // ---- exclusive prefix over cells ----
    int local[CELLS_PT];
    int sum = 0;
#pragma unroll
    for (int i = 0; i < CELLS_PT; ++i) { local[i] = s_hist[t * CELLS_PT + i]; sum += local[i]; }
    s_scan[t] = sum;
    __syncthreads();
    for (int off = 1; off < FPS_T; off <<= 1) {
        const int add = (t >= off) ? s_scan[t - off] : 0;
        __syncthreads();
        s_scan[t] += add;
        __syncthreads();
    }
    int base = s_scan[t] - sum;
#pragma unroll
    for (int i = 0; i < CELLS_PT; ++i) { s_hist[t * CELLS_PT + i] = base; base += local[i]; }
    __syncthreads();

    // ---- scatter into sorted order ----
#pragma unroll
    for (int j = 0; j < CPT; ++j) {
        const int g = t + j * FPS_T;
        const int pos = atomicAdd(&s_hist[cc[j]], 1);
        s_Px[pos] = rx[j]; s_Py[pos] = ry[j]; s_Pz[pos] = rz[j];
        s_G[pos] = (u16)g;
        if (g == 0) s_osel[0] = (u32)pos;   // (0<<13)|pos
    }
    __syncthreads();

    // ---- chunk bbox (registers) + d2 init (LDS, overwrites hist) ----
    float lox, hix, loy, hiy, loz, hiz;
    {
        const int p0 = t * CPT;
        lox = hix = s_Px[p0]; loy = hiy = s_Py[p0]; loz = hiz = s_Pz[p0];
        s_d2[p0] = __int_as_float(0x7f800000);
#pragma unroll
        for (int j = 1; j < CPT; ++j) {
            const float X = s_Px[p0 + j], Y = s_Py[p0 + j], Z = s_Pz[p0 + j];
            lox = fminf(lox, X); hix = fmaxf(hix, X);
            loy = fminf(loy, Y); hiy = fmaxf(hiy, Y);
            loz = fminf(loz, Z); hiz = fmaxf(hiz, Z);
            s_d2[p0 + j] = __int_as_float(0x7f800000);
        }
    }
    __syncthreads();

    // ---- phase B: process active chunks of this wave, 4 per pass ----
    auto phaseB = [&](u64 mk) {
        while (mk) {
            int c0, c1 = -1, c2 = -1, c3 = -1;
            c0 = (int)__builtin_ctzll(mk); mk &= mk - 1;
            if (mk) { c1 = (int)__builtin_ctzll(mk); mk &= mk - 1;
                if (mk) { c2 = (int)__builtin_ctzll(mk); mk &= mk - 1;
                    if (mk) { c3 = (int)__builtin_ctzll(mk); mk &= mk - 1; } } }
            const int sub = lane >> 4;
            int myc = c0;
            myc = (sub == 1) ? c1 : myc;
            myc = (sub == 2) ? c2 : myc;
            myc = (sub == 3) ? c3 : myc;
            if (myc >= 0) {
                const int cid = (w << 6) + myc;
                const int pp = cid * CPT + (lane & 15);
                const float X = s_Px[pp], Y = s_Py[pp], Z = s_Pz[pp];
                const float od = s_d2[pp];
                const float dx = __fsub_rn(X, qx);
                const float dy = __fsub_rn(Y, qy);
                const float dz = __fsub_rn(Z, qz);
                const float dist = __fadd_rn(
                    __fadd_rn(__fmul_rn(dx, dx), __fmul_rn(dy, dy)),
                    __fmul_rn(dz, dz));
                const float nd = fminf(od, dist);
                s_d2[pp] = nd;
                const u32 g = (u32)s_G[pp];
                u32 kh = __float_as_uint(nd);
                u32 kl = ((~g & 0x1FFFu) << 19) | ((u32)pp << 6);
                row_kmax(kh, kl);
                if ((lane & 15) == 15) s_ub[cid] = ((u64)kh << 32) | kl;
            }
        }
    };

    u32 cacheH = 0, cacheL = 0;   // lane63: cached reduced wave key

    // ---- epoch 0: all chunks update with q0 ----
    phaseB(~0ull);
    {
        const u64 kmy = s_ub[t];
        u32 rh = (u32)(kmy >> 32), rl = (u32)kmy;
        wave_kmax(rh, rl);
        if (lane == 63) { cacheH = rh; cacheL = rl; s_wkey[0][w] = ((u64)rh << 32) | rl; }
    }
    __syncthreads();

    // ---- main loop: one barrier per epoch ----
    for (int m = 1; m < Mn; ++m) {
        // select sample m from keys of previous epoch
        const u64* __restrict__ K = s_wkey[(m - 1) & 1];
        const u64 kk = u64max(u64max(u64max(K[0], K[1]), u64max(K[2], K[3])),
                              u64max(u64max(K[4], K[5]), u64max(K[6], K[7])));
        const u32 pos = (u32)(kk >> 6) & 0x1FFFu;
        if (t == 0) {
            const u32 g = (~(u32)(kk >> 19)) & 0x1FFFu;
            s_osel[m] = (g << 13) | pos;
        }
        qx = s_Px[pos]; qy = s_Py[pos]; qz = s_Pz[pos];   // broadcast reads

        // conservative skip test for my chunk
        const float ubv = __uint_as_float(((const u32*)s_ub)[2 * t + 1]);
        const float ddx = fmaxf(fmaxf(__fsub_rn(lox, qx), __fsub_rn(qx, hix)), 0.0f);
        const float ddy = fmaxf(fmaxf(__fsub_rn(loy, qy), __fsub_rn(qy, hiy)), 0.0f);
        const float ddz = fmaxf(fmaxf(__fsub_rn(loz, qz), __fsub_rn(qz, hiz)), 0.0f);
        const float Dmin2 = __fadd_rn(
            __fadd_rn(__fmul_rn(ddx, ddx), __fmul_rn(ddy, ddy)), __fmul_rn(ddz, ddz));
        const bool active = __fmul_rn(Dmin2, 0.99999f) < ubv;
        const u64 mk = __ballot(active);

        if (mk) {
            phaseB(mk);
            const u64 kmy = s_ub[t];
            u32 rh = (u32)(kmy >> 32), rl = (u32)kmy;
            wave_kmax(rh, rl);
            if (lane == 63) { cacheH = rh; cacheL = rl; }
        }
        if (lane == 63) s_wkey[m & 1][w] = ((u64)cacheH << 32) | cacheL;
        __syncthreads();
    }

    // ---- flush outputs ----
    float* __restrict__ o2 = out_p2 + (size_t)b * Mn * 3;
    float* __restrict__ oi = out_idxf + (size_t)b * Mn;
    for (int i = t; i < Mn; i += FPS_T) {
        const u32 sel = s_osel[i];
        const u32 pos = sel & 0x1FFFu;
        const u32 g = sel >> 13;
        oi[i] = (float)g;
        o2[i * 3 + 0] = s_Px[pos];
        o2[i * 3 + 1] = s_Py[pos];
        o2[i * 3 + 2] = s_Pz[pos];
    }
}

// ---------------------------------------------------------------------------
// kNN + feature mean (unchanged -- passed rounds 1/4/5/6/7).
// ---------------------------------------------------------------------------
#define KNN_WPB 4
__global__ __launch_bounds__(64 * KNN_WPB) void knn_mean_kernel(
    const float* __restrict__ p1,
    const float* __restrict__ x,
    const float* __restrict__ p2,
    float* __restrict__ y)
{
    const int lane = threadIdx.x & 63;
    const int wid  = threadIdx.x >> 6;
    const int q    = blockIdx.x * KNN_WPB + wid;    // 0 .. B*M-1
    const int b    = q >> 11;                        // q / Mn  (Mn = 2048)
    const float* __restrict__ P = p1 + (size_t)b * (Nn * 3);

    const float qx = p2[(size_t)q * 3 + 0];
    const float qy = p2[(size_t)q * 3 + 1];
    const float qz = p2[(size_t)q * 3 + 2];
    const float qq = __fadd_rn(
        __fadd_rn(__fmul_rn(qx, qx), __fmul_rn(qy, qy)), __fmul_rn(qz, qz));

    float slotv = __int_as_float(0x7f800000);
    int   sloti = 0x7fffffff;
    float thr   = __int_as_float(0x7f800000);
    int   thri  = 0x7fffffff;

    for (int c = 0; c < Nn / 64; ++c) {
        const int g = c * 64 + lane;
        const float ax = P[g * 3 + 0];
        const float ay = P[g * 3 + 1];
        const float az = P[g * 3 + 2];
        const float pp = __fadd_rn(
            __fadd_rn(__fmul_rn(ax, ax), __fmul_rn(ay, ay)), __fmul_rn(az, az));
        const float dot = __fmaf_rn(az, qz, __fmaf_rn(ay, qy, __fmul_rn(ax, qx)));
        const float d = __fsub_rn(__fadd_rn(qq, pp), __fmul_rn(2.0f, dot));
        const bool pass = (d < thr) || (d == thr && g < thri);
        unsigned long long ball = __ballot(pass);
        while (ball) {
            const int src = __builtin_ctzll(ball);
            ball &= ball - 1ull;
            const float v  = __shfl(d, src);
            const int   vi = __shfl(g, src);
            const float upv = __shfl_up(slotv, 1);
            const int   upi = __shfl_up(sloti, 1);
            const bool beforeme = (v < slotv) || (v == slotv && vi < sloti);
            bool beforeup = (v < upv) || (v == upv && vi < upi);
            if (lane == 0) beforeup = false;
            if (beforeme) {
                slotv = beforeup ? upv : v;
                sloti = beforeup ? upi : vi;
            }
            thr  = __shfl(slotv, 15);
            thri = __shfl(sloti, 15);
        }
    }

    float acc = 0.0f;
    const float* __restrict__ xb = x + (size_t)b * Nn * Cn;
#pragma unroll
    for (int s = 0; s < Kn; ++s) {
        const int ni = __shfl(sloti, s);
        acc = __fadd_rn(acc, xb[(size_t)ni * Cn + lane]);   // lane == channel
    }
    y[(size_t)q * Cn + lane] = __fmul_rn(acc, 0.0625f);
}

// ---------------------------------------------------------------------------
extern "C" void kernel_launch(void* const* d_in, const int* in_sizes, int n_in,
                              void* d_out, int out_size, void* d_ws, size_t ws_size,
                              hipStream_t stream) {
    const float* p1 = (const float*)d_in[0];
    const float* x  = (const float*)d_in[1];

    float* y    = (float*)d_out;                       // (B, M, C)
    float* p2   = y    + (size_t)Bn * Mn * Cn;         // (B, M, 3)
    float* idxf = p2   + (size_t)Bn * Mn * 3;          // (B, M) as float

    fps_kernel<<<Bn, FPS_T, 0, stream>>>(p1, p2, idxf);
    knn_mean_kernel<<<(Bn * Mn) / KNN_WPB, 64 * KNN_WPB, 0, stream>>>(p1, x, p2, y);
}

// Round 10
// 2574.279 us; speedup vs baseline: 1.2717x; 1.2717x over previous
//
#include <hip/hip_runtime.h>

#define Bn 8
#define Nn 8192
#define Cn 64
#define Mn 2048
#define Kn 16
#define FPS_T 512
#define CPT 16
#define NWAVE 8

typedef unsigned long long u64;
typedef unsigned u32;
typedef unsigned short u16;

__device__ __forceinline__ u64 u64max(u64 a, u64 b) { return a > b ? a : b; }
__device__ __forceinline__ int clampi(int v, int lo, int hi) { return v < lo ? lo : (v > hi ? hi : v); }

// ---- fused u64 (hi=valbits, lo=~g) DPP max; result in lane 63 (validated r7-r9).
template <int CTRL, int RMASK>
__device__ __forceinline__ void dpp_kmax_step(u32& hi, u32& lo) {
    const u32 h2 = (u32)__builtin_amdgcn_update_dpp((int)hi, (int)hi, CTRL, RMASK, 0xF, false);
    const u32 l2 = (u32)__builtin_amdgcn_update_dpp((int)lo, (int)lo, CTRL, RMASK, 0xF, false);
    const u64 a  = ((u64)hi << 32) | lo;
    const u64 b2 = ((u64)h2 << 32) | l2;
    if (b2 > a) { hi = h2; lo = l2; }
}
__device__ __forceinline__ void wave_kmax(u32& hi, u32& lo) {
    dpp_kmax_step<0x111, 0xF>(hi, lo);   // row_shr:1
    dpp_kmax_step<0x112, 0xF>(hi, lo);   // row_shr:2
    dpp_kmax_step<0x114, 0xF>(hi, lo);   // row_shr:4
    dpp_kmax_step<0x118, 0xF>(hi, lo);   // row_shr:8
    dpp_kmax_step<0x142, 0xA>(hi, lo);   // row_bcast:15
    dpp_kmax_step<0x143, 0xC>(hi, lo);   // row_bcast:31
}

// ---------------------------------------------------------------------------
// FPS. One block/batch, 512 threads (8 waves, 2/SIMD). Balanced kd-slab
// partition (x-rank slabs = waves, y-rank strips, z-rank chunks): compact
// chunk bboxes everywhere -> wave-level skip actually fires. Update loop is
// register-resident (r7-validated); chunk key = (d2bits<<32 | ~g). Per-wave
// slots carry key + winner coords (double-buffered, 1 barrier/iter).
// Arithmetic bit-identical to XLA (separate rn mul/add, no FMA); argmax
// tie-break = smallest original index via ~g key (validated r4-r9).
// ---------------------------------------------------------------------------
__global__ __launch_bounds__(FPS_T) void fps_kernel(
    const float* __restrict__ p1,
    float* __restrict__ out_p2,
    float* __restrict__ out_idxf)
{
    __shared__ float s_Px[Nn], s_Py[Nn], s_Pz[Nn];   // 96 KB, ORIGINAL order (by g)
    __shared__ u16   s_idx[2][Nn];                    // 32 KB ping-pong perm
    __shared__ u32   s_osel[Mn];                      // 8 KB: pass3 counters, then winners
    __shared__ int   s_hist[FPS_T];                   // 2 KB: pass1/pass2 counters+scan
    __shared__ u64   s_skey[2][NWAVE];
    __shared__ float s_sq[2][NWAVE][4];

    const int b = blockIdx.x, t = threadIdx.x, w = t >> 6, lane = t & 63;
    const float* __restrict__ P = p1 + (size_t)b * (Nn * 3);

    // ---- load coords (original order) ----
#pragma unroll
    for (int j = 0; j < CPT; ++j) {
        const int g = t + j * FPS_T;
        s_Px[g] = P[g * 3 + 0];
        s_Py[g] = P[g * 3 + 1];
        s_Pz[g] = P[g * 3 + 2];
    }
    if (t < 256) s_hist[t] = 0;
    __syncthreads();

    // ---- pass 1: counting sort by x (256 bins); slab = rank>>10 ----
    int xb[CPT];
#pragma unroll
    for (int j = 0; j < CPT; ++j) {
        const int g = t + j * FPS_T;
        xb[j] = clampi((int)((s_Px[g] + 4.0f) * 32.0f), 0, 255);
        atomicAdd(&s_hist[xb[j]], 1);
    }
    __syncthreads();
    {
        const int cnt = (t < 256) ? s_hist[t] : 0;
        int incl = cnt;
        for (int off = 1; off < 256; off <<= 1) {
            const int v = (t < 256 && t >= off) ? s_hist[t - off] : 0;
            __syncthreads();
            if (t < 256) { incl += v; s_hist[t] = incl; }
            __syncthreads();
        }
        if (t < 256) s_hist[t] = incl - cnt;   // exclusive base
    }
    __syncthreads();
#pragma unroll
    for (int j = 0; j < CPT; ++j) {
        const int g = t + j * FPS_T;
        const int r = atomicAdd(&s_hist[xb[j]], 1);
        s_idx[0][r] = (u16)g;
    }
    __syncthreads();

    // ---- pass 2: within each slab (1024), sort by y (64 bins); strip = rank>>7 ----
    s_hist[t] = 0;
    __syncthreads();
    int c2[CPT];
#pragma unroll
    for (int j = 0; j < CPT; ++j) {
        const int i = t + j * FPS_T;
        const int g = s_idx[0][i];
        const int yb = clampi((int)((s_Py[g] + 4.0f) * 8.0f), 0, 63);
        c2[j] = ((i >> 10) << 6) | yb;
        atomicAdd(&s_hist[c2[j]], 1);
    }
    __syncthreads();
    {
        const int cnt = s_hist[t];
        int incl = cnt;
        const int seg = t >> 6;
        for (int off = 1; off < 64; off <<= 1) {
            const int v = (t >= off && ((t - off) >> 6) == seg) ? s_hist[t - off] : 0;
            __syncthreads();
            incl += v; s_hist[t] = incl;
            __syncthreads();
        }
        s_hist[t] = (seg << 10) + incl - cnt;   // slab*1024 + exclusive
    }
    __syncthreads();
#pragma unroll
    for (int j = 0; j < CPT; ++j) {
        const int i = t + j * FPS_T;
        const u16 g = s_idx[0][i];
        const int r = atomicAdd(&s_hist[c2[j]], 1);
        s_idx[1][r] = g;
    }
    __syncthreads();

    // ---- pass 3: within each strip (128), sort by z (32 bins); chunk = 16 ----
    int* cnt3 = (int*)s_osel;   // 2048 counters
    for (int k = t; k < 2048; k += FPS_T) cnt3[k] = 0;
    __syncthreads();
    int c3[CPT];
#pragma unroll
    for (int j = 0; j < CPT; ++j) {
        const int i = t + j * FPS_T;
        const int g = s_idx[1][i];
        const int zb = clampi((int)((s_Pz[g] + 4.0f) * 4.0f), 0, 31);
        c3[j] = ((i >> 7) << 5) | zb;
        atomicAdd(&cnt3[c3[j]], 1);
    }
    __syncthreads();
    if (t < 64) {   // serial exclusive scan per strip; base = strip*128
        int acc = t << 7;
        for (int k = 0; k < 32; ++k) {
            const int c = cnt3[(t << 5) + k];
            cnt3[(t << 5) + k] = acc;
            acc += c;
        }
    }
    __syncthreads();
#pragma unroll
    for (int j = 0; j < CPT; ++j) {
        const int i = t + j * FPS_T;
        const u16 g = s_idx[1][i];
        const int r = atomicAdd(&cnt3[c3[j]], 1);
        s_idx[0][r] = g;
    }
    __syncthreads();

    // ---- gather my chunk into registers + bbox + key-lo constants ----
    float px[CPT], py[CPT], pz[CPT], d2[CPT];
    u32 kl[CPT];
    float lox, hix, loy, hiy, loz, hiz;
#pragma unroll
    for (int j = 0; j < CPT; ++j) {
        const int g = s_idx[0][t * CPT + j];
        const float X = s_Px[g], Y = s_Py[g], Z = s_Pz[g];
        px[j] = X; py[j] = Y; pz[j] = Z;
        kl[j] = (~(u32)g) & 0x1FFFu;
        d2[j] = __int_as_float(0x7f800000);
        if (j == 0) { lox = hix = X; loy = hiy = Y; loz = hiz = Z; }
        else {
            lox = fminf(lox, X); hix = fmaxf(hix, X);
            loy = fminf(loy, Y); hiy = fmaxf(hiy, Y);
            loz = fminf(loz, Z); hiz = fmaxf(hiz, Z);
        }
    }
    if (t == 0) s_osel[0] = 0u;

    float qx = s_Px[0], qy = s_Py[0], qz = s_Pz[0];
    u32 ubh = 0, ubl = 0;                       // my chunk's cached key
    u32 ckh = 0, ckl = 0;                       // lane63: cached wave key
    float cqx = 0.f, cqy = 0.f, cqz = 0.f;      // lane63: cached winner coords

    // ---- epoch 0: full update with q0 ----
    {
        u32 bh = 0u, bl = 0u;
#pragma unroll
        for (int j = 0; j < CPT; ++j) {
            const float dx = __fsub_rn(px[j], qx);
            const float dy = __fsub_rn(py[j], qy);
            const float dz = __fsub_rn(pz[j], qz);
            const float dist = __fadd_rn(
                __fadd_rn(__fmul_rn(dx, dx), __fmul_rn(dy, dy)), __fmul_rn(dz, dz));
            const float nd = fminf(d2[j], dist);
            d2[j] = nd;
            const u64 cand = ((u64)__float_as_uint(nd) << 32) | kl[j];
            if (cand > (((u64)bh << 32) | bl)) { bh = (u32)(cand >> 32); bl = (u32)cand; }
        }
        ubh = bh; ubl = bl;
        u32 rh = ubh, rl = ubl;
        wave_kmax(rh, rl);
        if (lane == 63) {
            ckh = rh; ckl = rl;
            const int gw = (int)((~rl) & 0x1FFFu);
            cqx = s_Px[gw]; cqy = s_Py[gw]; cqz = s_Pz[gw];
            s_skey[0][w] = ((u64)ckh << 32) | ckl;
            s_sq[0][w][0] = cqx; s_sq[0][w][1] = cqy; s_sq[0][w][2] = cqz;
        }
    }
    __syncthreads();

    // ---- main loop: one barrier per iteration ----
    for (int m = 1; m < Mn; ++m) {
        const int rb = (m - 1) & 1;
        u64 K[8]; float Q[8][3];
#pragma unroll
        for (int i = 0; i < 8; ++i) {
            K[i] = s_skey[rb][i];
            Q[i][0] = s_sq[rb][i][0];
            Q[i][1] = s_sq[rb][i][1];
            Q[i][2] = s_sq[rb][i][2];
        }
        u64 kk = K[0];
#pragma unroll
        for (int i = 1; i < 8; ++i) kk = u64max(kk, K[i]);
        qx = Q[0][0]; qy = Q[0][1]; qz = Q[0][2];
#pragma unroll
        for (int i = 1; i < 8; ++i) {
            const bool win = (K[i] == kk);
            qx = win ? Q[i][0] : qx;
            qy = win ? Q[i][1] : qy;
            qz = win ? Q[i][2] : qz;
        }
        if (t == 0) s_osel[m] = (~(u32)kk) & 0x1FFFu;

        // conservative chunk skip test (validated margin, r7)
        const float ubv = __uint_as_float(ubh);
        const float ddx = fmaxf(fmaxf(__fsub_rn(lox, qx), __fsub_rn(qx, hix)), 0.0f);
        const float ddy = fmaxf(fmaxf(__fsub_rn(loy, qy), __fsub_rn(qy, hiy)), 0.0f);
        const float ddz = fmaxf(fmaxf(__fsub_rn(loz, qz), __fsub_rn(qz, hiz)), 0.0f);
        const float Dmin2 = __fadd_rn(
            __fadd_rn(__fmul_rn(ddx, ddx), __fmul_rn(ddy, ddy)), __fmul_rn(ddz, ddz));
        const bool active = __fmul_rn(Dmin2, 0.99999f) < ubv;

        if (__ballot(active) != 0ull) {
            u32 bh = 0u, bl = 0u;
#pragma unroll
            for (int j = 0; j < CPT; ++j) {
                const float dx = __fsub_rn(px[j], qx);
                const float dy = __fsub_rn(py[j], qy);
                const float dz = __fsub_rn(pz[j], qz);
                const float dist = __fadd_rn(
                    __fadd_rn(__fmul_rn(dx, dx), __fmul_rn(dy, dy)), __fmul_rn(dz, dz));
                const float nd = fminf(d2[j], dist);
                d2[j] = nd;
                const u64 cand = ((u64)__float_as_uint(nd) << 32) | kl[j];
                if (cand > (((u64)bh << 32) | bl)) { bh = (u32)(cand >> 32); bl = (u32)cand; }
            }
            ubh = bh; ubl = bl;
            u32 rh = ubh, rl = ubl;
            wave_kmax(rh, rl);
            if (lane == 63) {
                ckh = rh; ckl = rl;
                const int gw = (int)((~rl) & 0x1FFFu);
                cqx = s_Px[gw]; cqy = s_Py[gw]; cqz = s_Pz[gw];
            }
        }
        if (lane == 63) {
            s_skey[m & 1][w] = ((u64)ckh << 32) | ckl;
            s_sq[m & 1][w][0] = cqx; s_sq[m & 1][w][1] = cqy; s_sq[m & 1][w][2] = cqz;
        }
        __syncthreads();
    }

    // ---- flush outputs (coords via original-index arrays) ----
    float* __restrict__ o2 = out_p2 + (size_t)b * Mn * 3;
    float* __restrict__ oi = out_idxf + (size_t)b * Mn;
    for (int i = t; i < Mn; i += FPS_T) {
        const u32 g = s_osel[i];
        oi[i] = (float)g;
        o2[i * 3 + 0] = s_Px[g];
        o2[i * 3 + 1] = s_Py[g];
        o2[i * 3 + 2] = s_Pz[g];
    }
}

// ---------------------------------------------------------------------------
// kNN + feature mean (unchanged -- passed rounds 1/4/5/6/7/9).
// ---------------------------------------------------------------------------
#define KNN_WPB 4
__global__ __launch_bounds__(64 * KNN_WPB) void knn_mean_kernel(
    const float* __restrict__ p1,
    const float* __restrict__ x,
    const float* __restrict__ p2,
    float* __restrict__ y)
{
    const int lane = threadIdx.x & 63;
    const int wid  = threadIdx.x >> 6;
    const int q    = blockIdx.x * KNN_WPB + wid;    // 0 .. B*M-1
    const int b    = q >> 11;                        // q / Mn  (Mn = 2048)
    const float* __restrict__ P = p1 + (size_t)b * (Nn * 3);

    const float qx = p2[(size_t)q * 3 + 0];
    const float qy = p2[(size_t)q * 3 + 1];
    const float qz = p2[(size_t)q * 3 + 2];
    const float qq = __fadd_rn(
        __fadd_rn(__fmul_rn(qx, qx), __fmul_rn(qy, qy)), __fmul_rn(qz, qz));

    float slotv = __int_as_float(0x7f800000);
    int   sloti = 0x7fffffff;
    float thr   = __int_as_float(0x7f800000);
    int   thri  = 0x7fffffff;

    for (int c = 0; c < Nn / 64; ++c) {
        const int g = c * 64 + lane;
        const float ax = P[g * 3 + 0];
        const float ay = P[g * 3 + 1];
        const float az = P[g * 3 + 2];
        const float pp = __fadd_rn(
            __fadd_rn(__fmul_rn(ax, ax), __fmul_rn(ay, ay)), __fmul_rn(az, az));
        const float dot = __fmaf_rn(az, qz, __fmaf_rn(ay, qy, __fmul_rn(ax, qx)));
        const float d = __fsub_rn(__fadd_rn(qq, pp), __fmul_rn(2.0f, dot));
        const bool pass = (d < thr) || (d == thr && g < thri);
        unsigned long long ball = __ballot(pass);
        while (ball) {
            const int src = __builtin_ctzll(ball);
            ball &= ball - 1ull;
            const float v  = __shfl(d, src);
            const int   vi = __shfl(g, src);
            const float upv = __shfl_up(slotv, 1);
            const int   upi = __shfl_up(sloti, 1);
            const bool beforeme = (v < slotv) || (v == slotv && vi < sloti);
            bool beforeup = (v < upv) || (v == upv && vi < upi);
            if (lane == 0) beforeup = false;
            if (beforeme) {
                slotv = beforeup ? upv : v;
                sloti = beforeup ? upi : vi;
            }
            thr  = __shfl(slotv, 15);
            thri = __shfl(sloti, 15);
        }
    }

    float acc = 0.0f;
    const float* __restrict__ xb = x + (size_t)b * Nn * Cn;
#pragma unroll
    for (int s = 0; s < Kn; ++s) {
        const int ni = __shfl(sloti, s);
        acc = __fadd_rn(acc, xb[(size_t)ni * Cn + lane]);   // lane == channel
    }
    y[(size_t)q * Cn + lane] = __fmul_rn(acc, 0.0625f);
}

// ---------------------------------------------------------------------------
extern "C" void kernel_launch(void* const* d_in, const int* in_sizes, int n_in,
                              void* d_out, int out_size, void* d_ws, size_t ws_size,
                              hipStream_t stream) {
    const float* p1 = (const float*)d_in[0];
    const float* x  = (const float*)d_in[1];

    float* y    = (float*)d_out;                       // (B, M, C)
    float* p2   = y    + (size_t)Bn * Mn * Cn;         // (B, M, 3)
    float* idxf = p2   + (size_t)Bn * Mn * 3;          // (B, M) as float

    fps_kernel<<<Bn, FPS_T, 0, stream>>>(p1, p2, idxf);
    knn_mean_kernel<<<(Bn * Mn) / KNN_WPB, 64 * KNN_WPB, 0, stream>>>(p1, x, p2, y);
}